// Round 16
// baseline (179.661 us; speedup 1.0000x reference)
//
#include <hip/hip_runtime.h>
#include <stdint.h>

#define NA   16000
#define KNN  10
#define NRES 400
#define APR  40
#define NCAT 12
#define BERT 1024
#define FF   128
#define DF1  256
#define DF2  64

using short8   = __attribute__((ext_vector_type(8))) short;
using floatx4  = __attribute__((ext_vector_type(4))) float;
using ushort4v = __attribute__((ext_vector_type(4))) unsigned short;
using ushort8v = __attribute__((ext_vector_type(8))) unsigned short;

__device__ __forceinline__ unsigned short bfc(float v) {
    return __builtin_bit_cast(unsigned short, (__bf16)v);
}
__device__ __forceinline__ float bflo(uint32_t u){ return __uint_as_float(u << 16); }
__device__ __forceinline__ float bfhi(uint32_t u){ return __uint_as_float(u & 0xffff0000u); }

// async global->LDS, 16B per lane
__device__ __forceinline__ void gload16(void* lds, const void* g) {
    __builtin_amdgcn_global_load_lds(
        (const __attribute__((address_space(1))) uint32_t*)g,
        (__attribute__((address_space(3))) uint32_t*)lds, 16, 0, 0);
}

// ---------------------------------------------------------------------------
// Weight prep.  WrT: 16 pre-swizzled 128x64 bf16 tiles; Bt3: 3 mats x 2
// tiles; W2T: [64][256] bf16.
// ---------------------------------------------------------------------------
__global__ void k_prep(const float* __restrict__ Wr,
                       const float* __restrict__ Wsv, const float* __restrict__ Wsr2,
                       const float* __restrict__ Wdr2, const float* __restrict__ Wf2,
                       unsigned short* __restrict__ WrT, unsigned short* __restrict__ Bt3,
                       unsigned short* __restrict__ W2T)
{
    int idx = blockIdx.x * 256 + threadIdx.x;
    if (idx < 16384) {
        int t = idx >> 10, rem = idx & 1023, n = rem >> 3, kq = rem & 7;
        ushort8v v;
#pragma unroll
        for (int e = 0; e < 8; ++e)
            v[e] = bfc(Wr[(size_t)(t * 64 + kq * 8 + e) * FF + n]);
        int ba = t * 16384 + ((n * 128 + kq * 16) ^ ((n & 7) << 4));
        *(ushort8v*)((char*)WrT + ba) = v;
    } else if (idx < 16384 + 6144) {
        int i2 = idx - 16384;
        int m = i2 >> 11, r2 = i2 & 2047;
        int t = r2 >> 10, r3 = r2 & 1023, n = r3 >> 3, kq = r3 & 7;
        const float* W = (m == 0) ? Wsv : ((m == 1) ? Wsr2 : Wdr2);
        ushort8v v;
#pragma unroll
        for (int e = 0; e < 8; ++e)
            v[e] = bfc(W[(size_t)(t * 64 + kq * 8 + e) * FF + n]);
        int ba = (m * 2 + t) * 16384 + ((n * 128 + kq * 16) ^ ((n & 7) << 4));
        *(ushort8v*)((char*)Bt3 + ba) = v;
    } else {
        int i3 = idx - 16384 - 6144;
        int n = i3 >> 8, k = i3 & 255;
        W2T[i3] = bfc(Wf2[(size_t)k * DF2 + n]);
    }
}

// ---------------------------------------------------------------------------
// MEGA 1: blockIdx.x < 16 -> atomsSD role (drains early, frees CUs);
//         blockIdx.x >= 16 -> big-GEMM role (r14 champion: BM=64, full K,
//         counted-vmcnt 3-stage pipeline, 48 KB LDS).
// GEMM: residues[16000,1024] @ Wr -> ACC fp32.
// atomsSD: SD[a][0:128]=bf16(atoms@Wsr1), [128:256]=bf16(atoms@Wdr1).
// ---------------------------------------------------------------------------
__global__ void __launch_bounds__(256)
k_mega1(const float* __restrict__ R0, const float* __restrict__ R1,
        const unsigned short* __restrict__ Bsw,
        const float* __restrict__ atoms0, const float* __restrict__ atoms1,
        const float* __restrict__ Wsr1, const float* __restrict__ Wdr1,
        float* __restrict__ OUT, unsigned short* __restrict__ SD)
{
    __shared__ __align__(16) unsigned short sA[2][64 * 64];    // 2 x 8 KB
    __shared__ __align__(16) unsigned short sB[2][128 * 64];   // 2 x 16 KB
    const int tid = threadIdx.x;

    if (blockIdx.x < 16) {
        // ---------------- atomsSD role ----------------
        float* sAt = (float*)sA;   // 3 KB carved from sA
        const int p = blockIdx.y;
        const float* atoms = p ? atoms1 : atoms0;
        unsigned short* SDp = SD + (size_t)p * 4096000;
        const int a0 = blockIdx.x * 1000;   // 16 blocks x 1000 atoms
        const int f = tid & 127, half = tid >> 7;

        float wsr[NCAT], wdr[NCAT];
#pragma unroll
        for (int c = 0; c < NCAT; ++c) {
            wsr[c] = Wsr1[c * FF + f];
            wdr[c] = Wdr1[c * FF + f];
        }

        for (int base = 0; base < 1000; base += 64) {
            int cnt = (1000 - base < 64) ? (1000 - base) : 64;
            __syncthreads();
            if (tid < cnt * 3)
                ((float4*)sAt)[tid] =
                    *(const float4*)&atoms[(size_t)(a0 + base) * NCAT + tid * 4];
            __syncthreads();
#pragma unroll 4
            for (int pass = 0; pass < 32; ++pass) {
                int ai = pass * 2 + half;
                if (ai < cnt) {
                    int a = a0 + base + ai;
                    float ss = 0.f, sd = 0.f;
#pragma unroll
                    for (int c = 0; c < NCAT; ++c) {
                        float ac = sAt[ai * NCAT + c];
                        ss = fmaf(ac, wsr[c], ss);
                        sd = fmaf(ac, wdr[c], sd);
                    }
                    SDp[(size_t)a * 256 + f]       = bfc(ss);
                    SDp[(size_t)a * 256 + 128 + f] = bfc(sd);
                }
            }
        }
        return;
    }

    // ---------------- GEMM role (r14 champion verbatim) ----------------
    const int l = tid & 63, w = tid >> 6;
    const int m0 = (blockIdx.x - 16) * 64;
    const float* A = blockIdx.y ? R1 : R0;
    float* C = OUT + (size_t)blockIdx.y * 2048000;

    floatx4 acc[4][2];
#pragma unroll
    for (int mt = 0; mt < 4; ++mt)
#pragma unroll
        for (int nt = 0; nt < 2; ++nt) acc[mt][nt] = (floatx4){0.f, 0.f, 0.f, 0.f};

    const int arow = tid >> 4, acol = (tid & 15) * 4;

    // ---- prologue ----
    {
        float4 a0r[4];
#pragma unroll
        for (int pass = 0; pass < 4; ++pass)
            a0r[pass] = *(const float4*)&A[(size_t)(m0 + pass * 16 + arow) * BERT + acol];
#pragma unroll
        for (int pass = 0; pass < 4; ++pass) {
            int row = pass * 16 + arow;
            ushort4v hv = {bfc(a0r[pass].x), bfc(a0r[pass].y), bfc(a0r[pass].z), bfc(a0r[pass].w)};
            *(ushort4v*)((char*)sA[0] + ((row * 128 + (tid & 15) * 8) ^ ((row & 7) << 4))) = hv;
        }
    }
    __builtin_amdgcn_sched_barrier(0);
    {
        const char* bs = (const char*)Bsw + tid * 16;
        char* bd = (char*)sB[0] + tid * 16;
#pragma unroll
        for (int q = 0; q < 4; ++q) gload16(bd + q * 4096, bs + q * 4096);
    }
    __builtin_amdgcn_sched_barrier(0);
    float4 aP[4], aQ[4];
#pragma unroll
    for (int pass = 0; pass < 4; ++pass)
        aP[pass] = *(const float4*)&A[(size_t)(m0 + pass * 16 + arow) * BERT + 64 + acol];
    __builtin_amdgcn_sched_barrier(0);
    asm volatile("s_waitcnt vmcnt(4) lgkmcnt(0)" ::: "memory");
    __builtin_amdgcn_sched_barrier(0);
    __builtin_amdgcn_s_barrier();
    __builtin_amdgcn_sched_barrier(0);

    auto step = [&](int t, int cur, float4* aC, float4* aN) {
        const int nxt = cur ^ 1;
        {
            int bt = (t + 1 < 16) ? t + 1 : 15;
            const char* bs = (const char*)Bsw + (size_t)bt * 16384 + tid * 16;
            char* bd = (char*)sB[nxt] + tid * 16;
#pragma unroll
            for (int q = 0; q < 4; ++q) gload16(bd + q * 4096, bs + q * 4096);
        }
        __builtin_amdgcn_sched_barrier(0);
        {
            int at2 = (t + 2 < 16) ? t + 2 : 15;
#pragma unroll
            for (int pass = 0; pass < 4; ++pass)
                aN[pass] = *(const float4*)&A[(size_t)(m0 + pass * 16 + arow) * BERT + at2 * 64 + acol];
        }
        __builtin_amdgcn_sched_barrier(0);
#pragma unroll
        for (int ks = 0; ks < 2; ++ks) {
            short8 ah[4], bh[2];
            const int kb = ks * 64 + (l >> 4) * 16;
#pragma unroll
            for (int mt = 0; mt < 4; ++mt) {
                int row = mt * 16 + (l & 15);
                ah[mt] = *(const short8*)((char*)sA[cur] + ((row * 128 + kb) ^ ((row & 7) << 4)));
            }
#pragma unroll
            for (int nt = 0; nt < 2; ++nt) {
                int row = w * 32 + nt * 16 + (l & 15);
                bh[nt] = *(const short8*)((char*)sB[cur] + ((row * 128 + kb) ^ ((row & 7) << 4)));
            }
#pragma unroll
            for (int mt = 0; mt < 4; ++mt)
#pragma unroll
                for (int nt = 0; nt < 2; ++nt)
                    acc[mt][nt] = __builtin_amdgcn_mfma_f32_16x16x32_bf16(ah[mt], bh[nt], acc[mt][nt], 0, 0, 0);
        }
        __builtin_amdgcn_sched_barrier(0);
#pragma unroll
        for (int pass = 0; pass < 4; ++pass) {
            int row = pass * 16 + arow;
            ushort4v hv = {bfc(aC[pass].x), bfc(aC[pass].y), bfc(aC[pass].z), bfc(aC[pass].w)};
            *(ushort4v*)((char*)sA[nxt] + ((row * 128 + (tid & 15) * 8) ^ ((row & 7) << 4))) = hv;
        }
        __builtin_amdgcn_sched_barrier(0);
        asm volatile("s_waitcnt vmcnt(4) lgkmcnt(0)" ::: "memory");
        __builtin_amdgcn_sched_barrier(0);
        __builtin_amdgcn_s_barrier();
        __builtin_amdgcn_sched_barrier(0);
    };
#pragma unroll
    for (int tt = 0; tt < 8; ++tt) {
        step(2 * tt,     0, aP, aQ);
        step(2 * tt + 1, 1, aQ, aP);
    }

#pragma unroll
    for (int mt = 0; mt < 4; ++mt)
#pragma unroll
        for (int nt = 0; nt < 2; ++nt)
#pragma unroll
            for (int r = 0; r < 4; ++r) {
                int row = m0 + mt * 16 + (l >> 4) * 4 + r;
                int col = w * 32 + nt * 16 + (l & 15);
                C[(size_t)row * FF + col] = acc[mt][nt][r];
            }
}

// ---------------------------------------------------------------------------
// FUSED gather1 + layer-2 GEMM.
// ---------------------------------------------------------------------------
__global__ void __launch_bounds__(256)
k_gl2(float* __restrict__ ACC, const unsigned short* __restrict__ SD,
      const unsigned short* __restrict__ Bt3,
      const int* __restrict__ sn0, const int* __restrict__ dn0,
      const int* __restrict__ sn1, const int* __restrict__ dn1,
      const float* __restrict__ atoms0, const float* __restrict__ atoms1,
      const float* __restrict__ Wv, unsigned short* __restrict__ SD2)
{
    __shared__ int sIdx[32][20];                         // 2.5 KB
    __shared__ float sWv[NCAT * FF];                     // 6 KB
    __shared__ float sAt[32 * NCAT];                     // 1.5 KB
    __shared__ __align__(16) unsigned short sZ[32 * 128];     // 8 KB swizzled
    __shared__ __align__(16) unsigned short sB[2][128 * 64];  // 32 KB
    const int tid = threadIdx.x, l = tid & 63, w = tid >> 6;
    const int p = blockIdx.y, m0 = blockIdx.x * 32;
    const int* sn = p ? sn1 : sn0;
    const int* dn = p ? dn1 : dn0;
    float* ACCp = ACC + (size_t)p * 2048000;
    const unsigned short* SDp = SD + (size_t)p * 4096000;
    unsigned short* SD2p = SD2 + (size_t)p * 4096000;

    for (int t = tid; t < 640; t += 256) {
        int at = t / 20, q = t - at * 20;
        sIdx[at][q] = (q < 10) ? sn[(m0 + at) * KNN + q] : dn[(m0 + at) * KNN + q - 10];
    }
    {
        const float* atoms = p ? atoms1 : atoms0;
        for (int i = tid; i < 384; i += 256)
            ((float4*)sWv)[i] = ((const float4*)Wv)[i];
        if (tid < 96)
            ((float4*)sAt)[tid] = *(const float4*)&atoms[(size_t)m0 * NCAT + tid * 4];
    }
    __syncthreads();

    // ---- phase A: gather -> sZ (8 threads/atom, 16 cols each) ----
    {
        const int at = tid >> 3, c = tid & 7;
        const int a = m0 + at;
        float ss[16], dd[16];
#pragma unroll
        for (int e = 0; e < 16; ++e) { ss[e] = 0.f; dd[e] = 0.f; }
        int sc = 0, dc = 0;
#pragma unroll
        for (int n = 0; n < KNN; ++n) {
            int is = sIdx[at][n];
            if (is > -1) {
                sc++;
                uint4 v0 = *(const uint4*)&SDp[(size_t)is * 256 + c * 16];
                uint4 v1 = *(const uint4*)&SDp[(size_t)is * 256 + c * 16 + 8];
                uint32_t vv[8] = {v0.x, v0.y, v0.z, v0.w, v1.x, v1.y, v1.z, v1.w};
#pragma unroll
                for (int q = 0; q < 8; ++q) { ss[2*q] += bflo(vv[q]); ss[2*q+1] += bfhi(vv[q]); }
            }
        }
#pragma unroll
        for (int n = 0; n < KNN; ++n) {
            int id = sIdx[at][10 + n];
            if (id > -1) {
                dc++;
                uint4 v0 = *(const uint4*)&SDp[(size_t)id * 256 + 128 + c * 16];
                uint4 v1 = *(const uint4*)&SDp[(size_t)id * 256 + 128 + c * 16 + 8];
                uint32_t vv[8] = {v0.x, v0.y, v0.z, v0.w, v1.x, v1.y, v1.z, v1.w};
#pragma unroll
                for (int q = 0; q < 8; ++q) { dd[2*q] += bflo(vv[q]); dd[2*q+1] += bfhi(vv[q]); }
            }
        }
        const float rs = 1.f / (sc > 0 ? (float)sc : 1.f);
        const float rd = 1.f / (dc > 0 ? (float)dc : 1.f);
        float ov[16];
        {
            const size_t base = (size_t)a * FF + c * 16;
            float4 q0 = *(const float4*)&ACCp[base];
            float4 q1 = *(const float4*)&ACCp[base + 4];
            float4 q2 = *(const float4*)&ACCp[base + 8];
            float4 q3 = *(const float4*)&ACCp[base + 12];
            ov[0]=q0.x; ov[1]=q0.y; ov[2]=q0.z; ov[3]=q0.w;
            ov[4]=q1.x; ov[5]=q1.y; ov[6]=q1.z; ov[7]=q1.w;
            ov[8]=q2.x; ov[9]=q2.y; ov[10]=q2.z; ov[11]=q2.w;
            ov[12]=q3.x; ov[13]=q3.y; ov[14]=q3.z; ov[15]=q3.w;
        }
#pragma unroll
        for (int cc = 0; cc < NCAT; ++cc) {
            float ac = sAt[at * NCAT + cc];
            const float* wp = &sWv[cc * FF + c * 16];
#pragma unroll
            for (int e = 0; e < 16; ++e) ov[e] = fmaf(ac, wp[e], ov[e]);
        }
        ushort8v z0, z1;
#pragma unroll
        for (int e = 0; e < 8; ++e) {
            z0[e] = bfc(fmaxf(fmaf(ss[e],     rs, fmaf(dd[e],     rd, ov[e])),     0.f));
            z1[e] = bfc(fmaxf(fmaf(ss[e + 8], rs, fmaf(dd[e + 8], rd, ov[e + 8])), 0.f));
        }
        int bb = at * 256 + c * 32;
        *(ushort8v*)((char*)sZ + ( bb        ^ ((at & 7) << 4))) = z0;
        *(ushort8v*)((char*)sZ + ((bb + 16) ^ ((at & 7) << 4))) = z1;
    }

    // ---- phase B: Z @ {Wsv, Wsr2, Wdr2} ----
    for (int mat = 0; mat < 3; ++mat) {
        __syncthreads();
#pragma unroll
        for (int t = 0; t < 2; ++t) {
            const char* bs = (const char*)Bt3 + (size_t)(mat * 2 + t) * 16384 + tid * 16;
#pragma unroll
            for (int q = 0; q < 4; ++q) gload16((char*)sB[t] + tid * 16 + q * 4096, bs + q * 4096);
        }
        __syncthreads();

        floatx4 acc[2][2];
#pragma unroll
        for (int mt = 0; mt < 2; ++mt)
#pragma unroll
            for (int nt = 0; nt < 2; ++nt) acc[mt][nt] = (floatx4){0.f, 0.f, 0.f, 0.f};

#pragma unroll
        for (int t = 0; t < 2; ++t)
#pragma unroll
            for (int ks = 0; ks < 2; ++ks) {
                short8 ah[2], bh[2];
                const int kb = ks * 64 + (l >> 4) * 16;
#pragma unroll
                for (int mt = 0; mt < 2; ++mt) {
                    int row = mt * 16 + (l & 15);
                    ah[mt] = *(const short8*)((char*)sZ +
                             ((row * 256 + t * 128 + kb) ^ ((row & 7) << 4)));
                }
#pragma unroll
                for (int nt = 0; nt < 2; ++nt) {
                    int row = w * 32 + nt * 16 + (l & 15);
                    bh[nt] = *(const short8*)((char*)sB[t] + ((row * 128 + kb) ^ ((row & 7) << 4)));
                }
#pragma unroll
                for (int mt = 0; mt < 2; ++mt)
#pragma unroll
                    for (int nt = 0; nt < 2; ++nt)
                        acc[mt][nt] = __builtin_amdgcn_mfma_f32_16x16x32_bf16(ah[mt], bh[nt], acc[mt][nt], 0, 0, 0);
            }

#pragma unroll
        for (int mt = 0; mt < 2; ++mt)
#pragma unroll
            for (int nt = 0; nt < 2; ++nt)
#pragma unroll
                for (int r = 0; r < 4; ++r) {
                    int row = m0 + mt * 16 + (l >> 4) * 4 + r;
                    int col = w * 32 + nt * 16 + (l & 15);
                    float v = acc[mt][nt][r];
                    if (mat == 0) ACCp[(size_t)row * FF + col] = v;
                    else          SD2p[(size_t)row * 256 + (mat - 1) * FF + col] = bfc(v);
                }
    }
}

// ---------------------------------------------------------------------------
// Gather 2 + residue mean + fused pairprep: one block per (residue, protein).
// ---------------------------------------------------------------------------
__global__ void __launch_bounds__(256)
k_gather_res(const float* __restrict__ ACC, const unsigned short* __restrict__ SD2,
             const int* __restrict__ sn0, const int* __restrict__ dn0,
             const int* __restrict__ sn1, const int* __restrict__ dn1,
             const float* __restrict__ Wf1, const float* __restrict__ bf1,
             float* __restrict__ A1, float* __restrict__ B1)
{
    __shared__ int sIdx[APR][20];      // 3.2 KB
    __shared__ float zpart[16][128];   // 8 KB
    const int tid = threadIdx.x;
    const int p = blockIdx.y, r = blockIdx.x;
    const int* sn = p ? sn1 : sn0;
    const int* dn = p ? dn1 : dn0;
    const float* ACCp = ACC + (size_t)p * 2048000;
    const unsigned short* SDp = SD2 + (size_t)p * 4096000;
    const int aBase = r * APR;

    for (int t = tid; t < APR * 20; t += 256) {
        int at = t / 20, q = t - at * 20;
        sIdx[at][q] = (q < 10) ? sn[(aBase + at) * KNN + q] : dn[(aBase + at) * KNN + q - 10];
    }
    __syncthreads();

    const int at = tid >> 4, c8 = tid & 15;
    float zs[8] = {0,0,0,0,0,0,0,0};
#pragma unroll
    for (int rep = 0; rep < 3; ++rep) {
        int ai = at + rep * 16;
        if (ai < APR) {
            int a = aBase + ai;
            float ss[8] = {0,0,0,0,0,0,0,0}, dd[8] = {0,0,0,0,0,0,0,0};
            int sc = 0, dc = 0;
#pragma unroll
            for (int n = 0; n < KNN; ++n) {
                int is = sIdx[ai][n];
                if (is > -1) {
                    sc++;
                    uint4 v = *(const uint4*)&SDp[(size_t)is * 256 + c8 * 8];
                    uint32_t vv[4] = {v.x, v.y, v.z, v.w};
#pragma unroll
                    for (int q = 0; q < 4; ++q) { ss[2*q] += bflo(vv[q]); ss[2*q+1] += bfhi(vv[q]); }
                }
            }
#pragma unroll
            for (int n = 0; n < KNN; ++n) {
                int id = sIdx[ai][10 + n];
                if (id > -1) {
                    dc++;
                    uint4 v = *(const uint4*)&SDp[(size_t)id * 256 + 128 + c8 * 8];
                    uint32_t vv[4] = {v.x, v.y, v.z, v.w};
#pragma unroll
                    for (int q = 0; q < 4; ++q) { dd[2*q] += bflo(vv[q]); dd[2*q+1] += bfhi(vv[q]); }
                }
            }
            const float rs = 1.f / (sc > 0 ? (float)sc : 1.f);
            const float rd = 1.f / (dc > 0 ? (float)dc : 1.f);
            float4 a0v = *(const float4*)&ACCp[(size_t)a * FF + c8 * 8];
            float4 a1v = *(const float4*)&ACCp[(size_t)a * FF + c8 * 8 + 4];
            float ov[8] = {a0v.x, a0v.y, a0v.z, a0v.w, a1v.x, a1v.y, a1v.z, a1v.w};
#pragma unroll
            for (int e = 0; e < 8; ++e)
                zs[e] += fmaxf(fmaf(ss[e], rs, fmaf(dd[e], rd, ov[e])), 0.f);
        }
    }
    *(float4*)&zpart[at][c8 * 8]     = (float4){zs[0], zs[1], zs[2], zs[3]};
    *(float4*)&zpart[at][c8 * 8 + 4] = (float4){zs[4], zs[5], zs[6], zs[7]};
    __syncthreads();
#pragma unroll
    for (int s = 8; s > 0; s >>= 1) {
        if (at < s) {
            float4 x0 = *(const float4*)&zpart[at + s][c8 * 8];
            float4 x1 = *(const float4*)&zpart[at + s][c8 * 8 + 4];
            float4 y0 = *(const float4*)&zpart[at][c8 * 8];
            float4 y1 = *(const float4*)&zpart[at][c8 * 8 + 4];
            y0.x += x0.x; y0.y += x0.y; y0.z += x0.z; y0.w += x0.w;
            y1.x += x1.x; y1.y += x1.y; y1.z += x1.z; y1.w += x1.w;
            *(float4*)&zpart[at][c8 * 8]     = y0;
            *(float4*)&zpart[at][c8 * 8 + 4] = y1;
        }
        __syncthreads();
    }

    // ---- fused pairprep ----
    {
        const int o = tid;   // 0..255
        const float* WfBase = Wf1 + (p ? (size_t)FF * DF1 : 0);
        float s = 0.f;
#pragma unroll 8
        for (int k = 0; k < FF; ++k)
            s = fmaf(zpart[0][k], WfBase[(size_t)k * DF1 + o], s);
        s *= (1.0f / APR);
        if (!p) s += bf1[o];
        float* dst = p ? B1 : A1;
        dst[(size_t)r * DF1 + o] = s;
    }
}

// ---------------------------------------------------------------------------
// Pair MLP via MFMA, register-built H.
// ---------------------------------------------------------------------------
__global__ void __launch_bounds__(256)
k_pairs_mfma(const float* __restrict__ A1, const float* __restrict__ B1,
             const unsigned short* __restrict__ W2T,
             const float* __restrict__ bf2, const float* __restrict__ Wf3,
             const float* __restrict__ bf3, float* __restrict__ out)
{
    __shared__ __align__(16) float sA1[16 * 256];            // 16 KB linear
    __shared__ __align__(16) float sB1[16 * 256];            // 16 KB, XOR (row&7)<<5
    __shared__ __align__(16) unsigned short sW[64 * 256];    // 32 KB, XOR (n&7)<<4
    const int tid = threadIdx.x, l = tid & 63, w = tid >> 6;
    const int i0 = blockIdx.x * 16, j0 = blockIdx.y * 16;

    for (int idx = tid; idx < 64 * 32; idx += 256) {
        int row = idx >> 5, c = idx & 31;
        int ba = (row * 512 + c * 16) ^ ((row & 7) << 4);
        *(uint4*)((char*)sW + ba) = *(const uint4*)(W2T + row * 256 + c * 8);
    }
    {
        int row = tid >> 4;
#pragma unroll
        for (int pass = 0; pass < 4; ++pass) {
            int coff = pass * 64 + (tid & 15) * 4;
            *(float4*)((char*)sA1 + row * 1024 + coff * 4) =
                *(const float4*)&A1[(size_t)(i0 + row) * DF1 + coff];
            int bb = (row * 1024 + coff * 4) ^ ((row & 7) << 5);
            *(float4*)((char*)sB1 + bb) =
                *(const float4*)&B1[(size_t)(j0 + row) * DF1 + coff];
        }
    }
    __syncthreads();

    floatx4 acc[4][4];
#pragma unroll
    for (int mt = 0; mt < 4; ++mt)
#pragma unroll
        for (int nt = 0; nt < 4; ++nt) acc[mt][nt] = (floatx4){0.f, 0.f, 0.f, 0.f};

    float b2r[4], w3r[4];
#pragma unroll
    for (int nt = 0; nt < 4; ++nt) {
        b2r[nt] = bf2[nt * 16 + (l & 15)];
        w3r[nt] = Wf3[nt * 16 + (l & 15)];
    }

    const int rB = l & 15, kq = l >> 4;
#pragma unroll
    for (int kc = 0; kc < 4; ++kc)
#pragma unroll
        for (int ks = 0; ks < 2; ++ks) {
            const int kfb = (kc * 64 + ks * 32 + kq * 8) * 4;
            float4 b1a = *(const float4*)((char*)sB1 + ((rB * 1024 + kfb)      ^ ((rB & 7) << 5)));
            float4 b1b = *(const float4*)((char*)sB1 + ((rB * 1024 + kfb + 16) ^ ((rB & 7) << 5)));
            short8 afr[4];
#pragma unroll
            for (int mt = 0; mt < 4; ++mt) {
                int rA = w * 4 + mt;
                float4 a1a = *(const float4*)((char*)sA1 + rA * 1024 + kfb);
                float4 a1b = *(const float4*)((char*)sA1 + rA * 1024 + kfb + 16);
                short8 hv;
                hv[0] = (short)bfc(fmaxf(a1a.x + b1a.x, 0.f));
                hv[1] = (short)bfc(fmaxf(a1a.y + b1a.y, 0.f));
                hv[2] = (short)bfc(fmaxf(a1a.z + b1a.z, 0.f));
                hv[3] = (short)bfc(fmaxf(a1a.w + b1a.w, 0.f));
                hv[4] = (short)bfc(fmaxf(a1b.x + b1b.x, 0.f));
                hv[5] = (short)bfc(fmaxf(a1b.y + b1b.y, 0.f));
                hv[6] = (short)bfc(fmaxf(a1b.z + b1b.z, 0.f));
                hv[7] = (short)bfc(fmaxf(a1b.w + b1b.w, 0.f));
                afr[mt] = hv;
            }
            const int kwb = kc * 128 + ks * 64 + kq * 16;
            short8 bfr[4];
#pragma unroll
            for (int nt = 0; nt < 4; ++nt) {
                int n = nt * 16 + (l & 15);
                bfr[nt] = *(const short8*)((char*)sW + ((n * 512 + kwb) ^ ((n & 7) << 4)));
            }
#pragma unroll
            for (int mt = 0; mt < 4; ++mt)
#pragma unroll
                for (int nt = 0; nt < 4; ++nt)
                    acc[mt][nt] = __builtin_amdgcn_mfma_f32_16x16x32_bf16(afr[mt], bfr[nt], acc[mt][nt], 0, 0, 0);
        }

    const float b3 = bf3[0];
#pragma unroll
    for (int mt = 0; mt < 4; ++mt)
#pragma unroll
        for (int r = 0; r < 4; ++r) {
            float s = 0.f;
#pragma unroll
            for (int nt = 0; nt < 4; ++nt)
                s += fmaxf(acc[mt][nt][r] + b2r[nt], 0.f) * w3r[nt];
            s += __shfl_xor(s, 1); s += __shfl_xor(s, 2);
            s += __shfl_xor(s, 4); s += __shfl_xor(s, 8);
            if ((l & 15) == 0) {
                int p = w * 64 + mt * 16 + (l >> 4) * 4 + r;
                out[(size_t)(i0 + (p >> 4)) * NRES + j0 + (p & 15)] = s + b3;
            }
        }
}

// ---------------------------------------------------------------------------
extern "C" void kernel_launch(void* const* d_in, const int* in_sizes, int n_in,
                              void* d_out, int out_size, void* d_ws, size_t ws_size,
                              hipStream_t stream)
{
    const float* atoms0    = (const float*)d_in[0];
    const float* residues0 = (const float*)d_in[1];
    const int*   same0     = (const int*)d_in[2];
    const int*   diff0     = (const int*)d_in[3];
    const float* atoms1    = (const float*)d_in[5];
    const float* residues1 = (const float*)d_in[6];
    const int*   same1     = (const int*)d_in[7];
    const int*   diff1     = (const int*)d_in[8];
    const float* Wv   = (const float*)d_in[10];
    const float* Wr   = (const float*)d_in[11];
    const float* Wsr1 = (const float*)d_in[12];
    const float* Wdr1 = (const float*)d_in[13];
    const float* Wsv  = (const float*)d_in[14];
    const float* Wsr2 = (const float*)d_in[15];
    const float* Wdr2 = (const float*)d_in[16];
    const float* Wf1  = (const float*)d_in[17];
    const float* bf1  = (const float*)d_in[18];
    const float* Wf2  = (const float*)d_in[19];
    const float* bf2  = (const float*)d_in[20];
    const float* Wf3  = (const float*)d_in[21];
    const float* bf3  = (const float*)d_in[22];

    float* ws  = (float*)d_ws;
    float* ACC = ws;                                         // 2 x 2,048,000 f
    unsigned short* SD  = (unsigned short*)(ws + 4096000);   // 2 x 4,096,000 u16 (layer-1)
    unsigned short* SD2 = (unsigned short*)(ws + 8192000);   // 2 x 4,096,000 u16 (layer-2)
    float* A1  = ws + 12288000;                              // 102,400 f
    float* B1  = ws + 12390400;                              // 102,400 f
    unsigned short* WrT = (unsigned short*)(ws + 12492800);  // 131,072 u16
    unsigned short* Bt3 = (unsigned short*)(ws + 12558336);  //  49,152 u16
    unsigned short* W2T = (unsigned short*)(ws + 12582912);  //  16,384 u16

    k_prep<<<152, 256, 0, stream>>>(Wr, Wsv, Wsr2, Wdr2, Wf2, WrT, Bt3, W2T);
    k_mega1<<<dim3(266, 2), 256, 0, stream>>>(residues0, residues1, WrT,
                                              atoms0, atoms1, Wsr1, Wdr1, ACC, SD);
    k_gl2<<<dim3(500, 2), 256, 0, stream>>>(ACC, SD, Bt3, same0, diff0, same1, diff1,
                                            atoms0, atoms1, Wv, SD2);
    k_gather_res<<<dim3(NRES, 2), 256, 0, stream>>>(ACC, SD2, same0, diff0, same1, diff1,
                                                    Wf1, bf1, A1, B1);
    k_pairs_mfma<<<dim3(25, 25), 256, 0, stream>>>(A1, B1, W2T, bf2, Wf3, bf3, (float*)d_out);
}

// Round 17
// 119.292 us; speedup vs baseline: 1.5061x; 1.5061x over previous
//
#include <hip/hip_runtime.h>
#include <stdint.h>

#define NA   16000
#define KNN  10
#define NRES 400
#define APR  40
#define NCAT 12
#define BERT 1024
#define FF   128
#define DF1  256
#define DF2  64

using short8   = __attribute__((ext_vector_type(8))) short;
using floatx4  = __attribute__((ext_vector_type(4))) float;
using ushort4v = __attribute__((ext_vector_type(4))) unsigned short;
using ushort8v = __attribute__((ext_vector_type(8))) unsigned short;

__device__ __forceinline__ unsigned short bfc(float v) {
    return __builtin_bit_cast(unsigned short, (__bf16)v);
}
__device__ __forceinline__ float bflo(uint32_t u){ return __uint_as_float(u << 16); }
__device__ __forceinline__ float bfhi(uint32_t u){ return __uint_as_float(u & 0xffff0000u); }

// async global->LDS, 16B per lane
__device__ __forceinline__ void gload16(void* lds, const void* g) {
    __builtin_amdgcn_global_load_lds(
        (const __attribute__((address_space(1))) uint32_t*)g,
        (__attribute__((address_space(3))) uint32_t*)lds, 16, 0, 0);
}

// ---------------------------------------------------------------------------
// Weight prep.  WrT: 16 pre-swizzled 128x64 bf16 tiles; Bt3: 3 mats x 2
// tiles; W2T: [64][256] bf16.
// ---------------------------------------------------------------------------
__global__ void k_prep(const float* __restrict__ Wr,
                       const float* __restrict__ Wsv, const float* __restrict__ Wsr2,
                       const float* __restrict__ Wdr2, const float* __restrict__ Wf2,
                       unsigned short* __restrict__ WrT, unsigned short* __restrict__ Bt3,
                       unsigned short* __restrict__ W2T)
{
    int idx = blockIdx.x * 256 + threadIdx.x;
    if (idx < 16384) {
        int t = idx >> 10, rem = idx & 1023, n = rem >> 3, kq = rem & 7;
        ushort8v v;
#pragma unroll
        for (int e = 0; e < 8; ++e)
            v[e] = bfc(Wr[(size_t)(t * 64 + kq * 8 + e) * FF + n]);
        int ba = t * 16384 + ((n * 128 + kq * 16) ^ ((n & 7) << 4));
        *(ushort8v*)((char*)WrT + ba) = v;
    } else if (idx < 16384 + 6144) {
        int i2 = idx - 16384;
        int m = i2 >> 11, r2 = i2 & 2047;
        int t = r2 >> 10, r3 = r2 & 1023, n = r3 >> 3, kq = r3 & 7;
        const float* W = (m == 0) ? Wsv : ((m == 1) ? Wsr2 : Wdr2);
        ushort8v v;
#pragma unroll
        for (int e = 0; e < 8; ++e)
            v[e] = bfc(W[(size_t)(t * 64 + kq * 8 + e) * FF + n]);
        int ba = (m * 2 + t) * 16384 + ((n * 128 + kq * 16) ^ ((n & 7) << 4));
        *(ushort8v*)((char*)Bt3 + ba) = v;
    } else {
        int i3 = idx - 16384 - 6144;
        int n = i3 >> 8, k = i3 & 255;
        W2T[i3] = bfc(Wf2[(size_t)k * DF2 + n]);
    }
}

// ---------------------------------------------------------------------------
// MEGA 1 (r14 champion): blockIdx.x < 250 -> big-GEMM role (BM=64, full K,
// counted-vmcnt 3-stage pipeline); x >= 250 -> atomsSD role (64 atoms/block).
// GEMM: residues[16000,1024] @ Wr -> ACC fp32.
// atomsSD: SD[a][0:128]=bf16(atoms@Wsr1), [128:256]=bf16(atoms@Wdr1).
// ---------------------------------------------------------------------------
__global__ void __launch_bounds__(256)
k_mega1(const float* __restrict__ R0, const float* __restrict__ R1,
        const unsigned short* __restrict__ Bsw,
        const float* __restrict__ atoms0, const float* __restrict__ atoms1,
        const float* __restrict__ Wsr1, const float* __restrict__ Wdr1,
        float* __restrict__ OUT, unsigned short* __restrict__ SD)
{
    __shared__ __align__(16) unsigned short sA[2][64 * 64];    // 2 x 8 KB
    __shared__ __align__(16) unsigned short sB[2][128 * 64];   // 2 x 16 KB
    const int tid = threadIdx.x;

    if (blockIdx.x >= 250) {
        // ---------------- atomsSD role ----------------
        float* sAt = (float*)sA;   // 3 KB carved from sA
        const int p = blockIdx.y;
        const float* atoms = p ? atoms1 : atoms0;
        unsigned short* SDp = SD + (size_t)p * 4096000;
        const int a0 = (blockIdx.x - 250) * 64;
        const int f = tid & 127, half = tid >> 7;

        if (tid < 192)
            ((float4*)sAt)[tid] = *(const float4*)&atoms[(size_t)a0 * NCAT + tid * 4];

        float wsr[NCAT], wdr[NCAT];
#pragma unroll
        for (int c = 0; c < NCAT; ++c) {
            wsr[c] = Wsr1[c * FF + f];
            wdr[c] = Wdr1[c * FF + f];
        }
        __syncthreads();

#pragma unroll 4
        for (int pass = 0; pass < 32; ++pass) {
            int ai = pass * 2 + half;
            int a = a0 + ai;
            float ss = 0.f, sd = 0.f;
#pragma unroll
            for (int c = 0; c < NCAT; ++c) {
                float ac = sAt[ai * NCAT + c];
                ss = fmaf(ac, wsr[c], ss);
                sd = fmaf(ac, wdr[c], sd);
            }
            SDp[(size_t)a * 256 + f]       = bfc(ss);
            SDp[(size_t)a * 256 + 128 + f] = bfc(sd);
        }
        return;
    }

    // ---------------- GEMM role (champion verbatim) ----------------
    const int l = tid & 63, w = tid >> 6;
    const int m0 = blockIdx.x * 64;
    const float* A = blockIdx.y ? R1 : R0;
    float* C = OUT + (size_t)blockIdx.y * 2048000;

    floatx4 acc[4][2];
#pragma unroll
    for (int mt = 0; mt < 4; ++mt)
#pragma unroll
        for (int nt = 0; nt < 2; ++nt) acc[mt][nt] = (floatx4){0.f, 0.f, 0.f, 0.f};

    const int arow = tid >> 4, acol = (tid & 15) * 4;

    // ---- prologue ----
    {
        float4 a0r[4];
#pragma unroll
        for (int pass = 0; pass < 4; ++pass)
            a0r[pass] = *(const float4*)&A[(size_t)(m0 + pass * 16 + arow) * BERT + acol];
#pragma unroll
        for (int pass = 0; pass < 4; ++pass) {
            int row = pass * 16 + arow;
            ushort4v hv = {bfc(a0r[pass].x), bfc(a0r[pass].y), bfc(a0r[pass].z), bfc(a0r[pass].w)};
            *(ushort4v*)((char*)sA[0] + ((row * 128 + (tid & 15) * 8) ^ ((row & 7) << 4))) = hv;
        }
    }
    __builtin_amdgcn_sched_barrier(0);
    {
        const char* bs = (const char*)Bsw + tid * 16;
        char* bd = (char*)sB[0] + tid * 16;
#pragma unroll
        for (int q = 0; q < 4; ++q) gload16(bd + q * 4096, bs + q * 4096);
    }
    __builtin_amdgcn_sched_barrier(0);
    float4 aP[4], aQ[4];
#pragma unroll
    for (int pass = 0; pass < 4; ++pass)
        aP[pass] = *(const float4*)&A[(size_t)(m0 + pass * 16 + arow) * BERT + 64 + acol];
    __builtin_amdgcn_sched_barrier(0);
    asm volatile("s_waitcnt vmcnt(4) lgkmcnt(0)" ::: "memory");
    __builtin_amdgcn_sched_barrier(0);
    __builtin_amdgcn_s_barrier();
    __builtin_amdgcn_sched_barrier(0);

    auto step = [&](int t, int cur, float4* aC, float4* aN) {
        const int nxt = cur ^ 1;
        {
            int bt = (t + 1 < 16) ? t + 1 : 15;
            const char* bs = (const char*)Bsw + (size_t)bt * 16384 + tid * 16;
            char* bd = (char*)sB[nxt] + tid * 16;
#pragma unroll
            for (int q = 0; q < 4; ++q) gload16(bd + q * 4096, bs + q * 4096);
        }
        __builtin_amdgcn_sched_barrier(0);
        {
            int at2 = (t + 2 < 16) ? t + 2 : 15;
#pragma unroll
            for (int pass = 0; pass < 4; ++pass)
                aN[pass] = *(const float4*)&A[(size_t)(m0 + pass * 16 + arow) * BERT + at2 * 64 + acol];
        }
        __builtin_amdgcn_sched_barrier(0);
#pragma unroll
        for (int ks = 0; ks < 2; ++ks) {
            short8 ah[4], bh[2];
            const int kb = ks * 64 + (l >> 4) * 16;
#pragma unroll
            for (int mt = 0; mt < 4; ++mt) {
                int row = mt * 16 + (l & 15);
                ah[mt] = *(const short8*)((char*)sA[cur] + ((row * 128 + kb) ^ ((row & 7) << 4)));
            }
#pragma unroll
            for (int nt = 0; nt < 2; ++nt) {
                int row = w * 32 + nt * 16 + (l & 15);
                bh[nt] = *(const short8*)((char*)sB[cur] + ((row * 128 + kb) ^ ((row & 7) << 4)));
            }
#pragma unroll
            for (int mt = 0; mt < 4; ++mt)
#pragma unroll
                for (int nt = 0; nt < 2; ++nt)
                    acc[mt][nt] = __builtin_amdgcn_mfma_f32_16x16x32_bf16(ah[mt], bh[nt], acc[mt][nt], 0, 0, 0);
        }
        __builtin_amdgcn_sched_barrier(0);
#pragma unroll
        for (int pass = 0; pass < 4; ++pass) {
            int row = pass * 16 + arow;
            ushort4v hv = {bfc(aC[pass].x), bfc(aC[pass].y), bfc(aC[pass].z), bfc(aC[pass].w)};
            *(ushort4v*)((char*)sA[nxt] + ((row * 128 + (tid & 15) * 8) ^ ((row & 7) << 4))) = hv;
        }
        __builtin_amdgcn_sched_barrier(0);
        asm volatile("s_waitcnt vmcnt(4) lgkmcnt(0)" ::: "memory");
        __builtin_amdgcn_sched_barrier(0);
        __builtin_amdgcn_s_barrier();
        __builtin_amdgcn_sched_barrier(0);
    };
#pragma unroll
    for (int tt = 0; tt < 8; ++tt) {
        step(2 * tt,     0, aP, aQ);
        step(2 * tt + 1, 1, aQ, aP);
    }

#pragma unroll
    for (int mt = 0; mt < 4; ++mt)
#pragma unroll
        for (int nt = 0; nt < 2; ++nt)
#pragma unroll
            for (int r = 0; r < 4; ++r) {
                int row = m0 + mt * 16 + (l >> 4) * 4 + r;
                int col = w * 32 + nt * 16 + (l & 15);
                C[(size_t)row * FF + col] = acc[mt][nt][r];
            }
}

// ---------------------------------------------------------------------------
// FUSED gather1 + layer-2 GEMM.
// ---------------------------------------------------------------------------
__global__ void __launch_bounds__(256)
k_gl2(float* __restrict__ ACC, const unsigned short* __restrict__ SD,
      const unsigned short* __restrict__ Bt3,
      const int* __restrict__ sn0, const int* __restrict__ dn0,
      const int* __restrict__ sn1, const int* __restrict__ dn1,
      const float* __restrict__ atoms0, const float* __restrict__ atoms1,
      const float* __restrict__ Wv, unsigned short* __restrict__ SD2)
{
    __shared__ int sIdx[32][20];                         // 2.5 KB
    __shared__ float sWv[NCAT * FF];                     // 6 KB
    __shared__ float sAt[32 * NCAT];                     // 1.5 KB
    __shared__ __align__(16) unsigned short sZ[32 * 128];     // 8 KB swizzled
    __shared__ __align__(16) unsigned short sB[2][128 * 64];  // 32 KB
    const int tid = threadIdx.x, l = tid & 63, w = tid >> 6;
    const int p = blockIdx.y, m0 = blockIdx.x * 32;
    const int* sn = p ? sn1 : sn0;
    const int* dn = p ? dn1 : dn0;
    float* ACCp = ACC + (size_t)p * 2048000;
    const unsigned short* SDp = SD + (size_t)p * 4096000;
    unsigned short* SD2p = SD2 + (size_t)p * 4096000;

    for (int t = tid; t < 640; t += 256) {
        int at = t / 20, q = t - at * 20;
        sIdx[at][q] = (q < 10) ? sn[(m0 + at) * KNN + q] : dn[(m0 + at) * KNN + q - 10];
    }
    {
        const float* atoms = p ? atoms1 : atoms0;
        for (int i = tid; i < 384; i += 256)
            ((float4*)sWv)[i] = ((const float4*)Wv)[i];
        if (tid < 96)
            ((float4*)sAt)[tid] = *(const float4*)&atoms[(size_t)m0 * NCAT + tid * 4];
    }
    __syncthreads();

    // ---- phase A: gather -> sZ (8 threads/atom, 16 cols each) ----
    {
        const int at = tid >> 3, c = tid & 7;
        const int a = m0 + at;
        float ss[16], dd[16];
#pragma unroll
        for (int e = 0; e < 16; ++e) { ss[e] = 0.f; dd[e] = 0.f; }
        int sc = 0, dc = 0;
#pragma unroll
        for (int n = 0; n < KNN; ++n) {
            int is = sIdx[at][n];
            if (is > -1) {
                sc++;
                uint4 v0 = *(const uint4*)&SDp[(size_t)is * 256 + c * 16];
                uint4 v1 = *(const uint4*)&SDp[(size_t)is * 256 + c * 16 + 8];
                uint32_t vv[8] = {v0.x, v0.y, v0.z, v0.w, v1.x, v1.y, v1.z, v1.w};
#pragma unroll
                for (int q = 0; q < 8; ++q) { ss[2*q] += bflo(vv[q]); ss[2*q+1] += bfhi(vv[q]); }
            }
        }
#pragma unroll
        for (int n = 0; n < KNN; ++n) {
            int id = sIdx[at][10 + n];
            if (id > -1) {
                dc++;
                uint4 v0 = *(const uint4*)&SDp[(size_t)id * 256 + 128 + c * 16];
                uint4 v1 = *(const uint4*)&SDp[(size_t)id * 256 + 128 + c * 16 + 8];
                uint32_t vv[8] = {v0.x, v0.y, v0.z, v0.w, v1.x, v1.y, v1.z, v1.w};
#pragma unroll
                for (int q = 0; q < 8; ++q) { dd[2*q] += bflo(vv[q]); dd[2*q+1] += bfhi(vv[q]); }
            }
        }
        const float rs = 1.f / (sc > 0 ? (float)sc : 1.f);
        const float rd = 1.f / (dc > 0 ? (float)dc : 1.f);
        float ov[16];
        {
            const size_t base = (size_t)a * FF + c * 16;
            float4 q0 = *(const float4*)&ACCp[base];
            float4 q1 = *(const float4*)&ACCp[base + 4];
            float4 q2 = *(const float4*)&ACCp[base + 8];
            float4 q3 = *(const float4*)&ACCp[base + 12];
            ov[0]=q0.x; ov[1]=q0.y; ov[2]=q0.z; ov[3]=q0.w;
            ov[4]=q1.x; ov[5]=q1.y; ov[6]=q1.z; ov[7]=q1.w;
            ov[8]=q2.x; ov[9]=q2.y; ov[10]=q2.z; ov[11]=q2.w;
            ov[12]=q3.x; ov[13]=q3.y; ov[14]=q3.z; ov[15]=q3.w;
        }
#pragma unroll
        for (int cc = 0; cc < NCAT; ++cc) {
            float ac = sAt[at * NCAT + cc];
            const float* wp = &sWv[cc * FF + c * 16];
#pragma unroll
            for (int e = 0; e < 16; ++e) ov[e] = fmaf(ac, wp[e], ov[e]);
        }
        ushort8v z0, z1;
#pragma unroll
        for (int e = 0; e < 8; ++e) {
            z0[e] = bfc(fmaxf(fmaf(ss[e],     rs, fmaf(dd[e],     rd, ov[e])),     0.f));
            z1[e] = bfc(fmaxf(fmaf(ss[e + 8], rs, fmaf(dd[e + 8], rd, ov[e + 8])), 0.f));
        }
        int bb = at * 256 + c * 32;
        *(ushort8v*)((char*)sZ + ( bb        ^ ((at & 7) << 4))) = z0;
        *(ushort8v*)((char*)sZ + ((bb + 16) ^ ((at & 7) << 4))) = z1;
    }

    // ---- phase B: Z @ {Wsv, Wsr2, Wdr2} ----
    for (int mat = 0; mat < 3; ++mat) {
        __syncthreads();
#pragma unroll
        for (int t = 0; t < 2; ++t) {
            const char* bs = (const char*)Bt3 + (size_t)(mat * 2 + t) * 16384 + tid * 16;
#pragma unroll
            for (int q = 0; q < 4; ++q) gload16((char*)sB[t] + tid * 16 + q * 4096, bs + q * 4096);
        }
        __syncthreads();

        floatx4 acc[2][2];
#pragma unroll
        for (int mt = 0; mt < 2; ++mt)
#pragma unroll
            for (int nt = 0; nt < 2; ++nt) acc[mt][nt] = (floatx4){0.f, 0.f, 0.f, 0.f};

#pragma unroll
        for (int t = 0; t < 2; ++t)
#pragma unroll
            for (int ks = 0; ks < 2; ++ks) {
                short8 ah[2], bh[2];
                const int kb = ks * 64 + (l >> 4) * 16;
#pragma unroll
                for (int mt = 0; mt < 2; ++mt) {
                    int row = mt * 16 + (l & 15);
                    ah[mt] = *(const short8*)((char*)sZ +
                             ((row * 256 + t * 128 + kb) ^ ((row & 7) << 4)));
                }
#pragma unroll
                for (int nt = 0; nt < 2; ++nt) {
                    int row = w * 32 + nt * 16 + (l & 15);
                    bh[nt] = *(const short8*)((char*)sB[t] + ((row * 128 + kb) ^ ((row & 7) << 4)));
                }
#pragma unroll
                for (int mt = 0; mt < 2; ++mt)
#pragma unroll
                    for (int nt = 0; nt < 2; ++nt)
                        acc[mt][nt] = __builtin_amdgcn_mfma_f32_16x16x32_bf16(ah[mt], bh[nt], acc[mt][nt], 0, 0, 0);
            }

#pragma unroll
        for (int mt = 0; mt < 2; ++mt)
#pragma unroll
            for (int nt = 0; nt < 2; ++nt)
#pragma unroll
                for (int r = 0; r < 4; ++r) {
                    int row = m0 + mt * 16 + (l >> 4) * 4 + r;
                    int col = w * 32 + nt * 16 + (l & 15);
                    float v = acc[mt][nt][r];
                    if (mat == 0) ACCp[(size_t)row * FF + col] = v;
                    else          SD2p[(size_t)row * 256 + (mat - 1) * FF + col] = bfc(v);
                }
    }
}

// ---------------------------------------------------------------------------
// Gather 2 + residue mean + fused pairprep: one block per (residue, protein).
// ---------------------------------------------------------------------------
__global__ void __launch_bounds__(256)
k_gather_res(const float* __restrict__ ACC, const unsigned short* __restrict__ SD2,
             const int* __restrict__ sn0, const int* __restrict__ dn0,
             const int* __restrict__ sn1, const int* __restrict__ dn1,
             const float* __restrict__ Wf1, const float* __restrict__ bf1,
             float* __restrict__ A1, float* __restrict__ B1)
{
    __shared__ int sIdx[APR][20];      // 3.2 KB
    __shared__ float zpart[16][128];   // 8 KB
    const int tid = threadIdx.x;
    const int p = blockIdx.y, r = blockIdx.x;
    const int* sn = p ? sn1 : sn0;
    const int* dn = p ? dn1 : dn0;
    const float* ACCp = ACC + (size_t)p * 2048000;
    const unsigned short* SDp = SD2 + (size_t)p * 4096000;
    const int aBase = r * APR;

    for (int t = tid; t < APR * 20; t += 256) {
        int at = t / 20, q = t - at * 20;
        sIdx[at][q] = (q < 10) ? sn[(aBase + at) * KNN + q] : dn[(aBase + at) * KNN + q - 10];
    }
    __syncthreads();

    const int at = tid >> 4, c8 = tid & 15;
    float zs[8] = {0,0,0,0,0,0,0,0};
#pragma unroll
    for (int rep = 0; rep < 3; ++rep) {
        int ai = at + rep * 16;
        if (ai < APR) {
            int a = aBase + ai;
            float ss[8] = {0,0,0,0,0,0,0,0}, dd[8] = {0,0,0,0,0,0,0,0};
            int sc = 0, dc = 0;
#pragma unroll
            for (int n = 0; n < KNN; ++n) {
                int is = sIdx[ai][n];
                if (is > -1) {
                    sc++;
                    uint4 v = *(const uint4*)&SDp[(size_t)is * 256 + c8 * 8];
                    uint32_t vv[4] = {v.x, v.y, v.z, v.w};
#pragma unroll
                    for (int q = 0; q < 4; ++q) { ss[2*q] += bflo(vv[q]); ss[2*q+1] += bfhi(vv[q]); }
                }
            }
#pragma unroll
            for (int n = 0; n < KNN; ++n) {
                int id = sIdx[ai][10 + n];
                if (id > -1) {
                    dc++;
                    uint4 v = *(const uint4*)&SDp[(size_t)id * 256 + 128 + c8 * 8];
                    uint32_t vv[4] = {v.x, v.y, v.z, v.w};
#pragma unroll
                    for (int q = 0; q < 4; ++q) { dd[2*q] += bflo(vv[q]); dd[2*q+1] += bfhi(vv[q]); }
                }
            }
            const float rs = 1.f / (sc > 0 ? (float)sc : 1.f);
            const float rd = 1.f / (dc > 0 ? (float)dc : 1.f);
            float4 a0v = *(const float4*)&ACCp[(size_t)a * FF + c8 * 8];
            float4 a1v = *(const float4*)&ACCp[(size_t)a * FF + c8 * 8 + 4];
            float ov[8] = {a0v.x, a0v.y, a0v.z, a0v.w, a1v.x, a1v.y, a1v.z, a1v.w};
#pragma unroll
            for (int e = 0; e < 8; ++e)
                zs[e] += fmaxf(fmaf(ss[e], rs, fmaf(dd[e], rd, ov[e])), 0.f);
        }
    }
    *(float4*)&zpart[at][c8 * 8]     = (float4){zs[0], zs[1], zs[2], zs[3]};
    *(float4*)&zpart[at][c8 * 8 + 4] = (float4){zs[4], zs[5], zs[6], zs[7]};
    __syncthreads();
#pragma unroll
    for (int s = 8; s > 0; s >>= 1) {
        if (at < s) {
            float4 x0 = *(const float4*)&zpart[at + s][c8 * 8];
            float4 x1 = *(const float4*)&zpart[at + s][c8 * 8 + 4];
            float4 y0 = *(const float4*)&zpart[at][c8 * 8];
            float4 y1 = *(const float4*)&zpart[at][c8 * 8 + 4];
            y0.x += x0.x; y0.y += x0.y; y0.z += x0.z; y0.w += x0.w;
            y1.x += x1.x; y1.y += x1.y; y1.z += x1.z; y1.w += x1.w;
            *(float4*)&zpart[at][c8 * 8]     = y0;
            *(float4*)&zpart[at][c8 * 8 + 4] = y1;
        }
        __syncthreads();
    }

    // ---- fused pairprep ----
    {
        const int o = tid;   // 0..255
        const float* WfBase = Wf1 + (p ? (size_t)FF * DF1 : 0);
        float s = 0.f;
#pragma unroll 8
        for (int k = 0; k < FF; ++k)
            s = fmaf(zpart[0][k], WfBase[(size_t)k * DF1 + o], s);
        s *= (1.0f / APR);
        if (!p) s += bf1[o];
        float* dst = p ? B1 : A1;
        dst[(size_t)r * DF1 + o] = s;
    }
}

// ---------------------------------------------------------------------------
// Pair MLP via MFMA, register-built H.
// ---------------------------------------------------------------------------
__global__ void __launch_bounds__(256)
k_pairs_mfma(const float* __restrict__ A1, const float* __restrict__ B1,
             const unsigned short* __restrict__ W2T,
             const float* __restrict__ bf2, const float* __restrict__ Wf3,
             const float* __restrict__ bf3, float* __restrict__ out)
{
    __shared__ __align__(16) float sA1[16 * 256];            // 16 KB linear
    __shared__ __align__(16) float sB1[16 * 256];            // 16 KB, XOR (row&7)<<5
    __shared__ __align__(16) unsigned short sW[64 * 256];    // 32 KB, XOR (n&7)<<4
    const int tid = threadIdx.x, l = tid & 63, w = tid >> 6;
    const int i0 = blockIdx.x * 16, j0 = blockIdx.y * 16;

    for (int idx = tid; idx < 64 * 32; idx += 256) {
        int row = idx >> 5, c = idx & 31;
        int ba = (row * 512 + c * 16) ^ ((row & 7) << 4);
        *(uint4*)((char*)sW + ba) = *(const uint4*)(W2T + row * 256 + c * 8);
    }
    {
        int row = tid >> 4;
#pragma unroll
        for (int pass = 0; pass < 4; ++pass) {
            int coff = pass * 64 + (tid & 15) * 4;
            *(float4*)((char*)sA1 + row * 1024 + coff * 4) =
                *(const float4*)&A1[(size_t)(i0 + row) * DF1 + coff];
            int bb = (row * 1024 + coff * 4) ^ ((row & 7) << 5);
            *(float4*)((char*)sB1 + bb) =
                *(const float4*)&B1[(size_t)(j0 + row) * DF1 + coff];
        }
    }
    __syncthreads();

    floatx4 acc[4][4];
#pragma unroll
    for (int mt = 0; mt < 4; ++mt)
#pragma unroll
        for (int nt = 0; nt < 4; ++nt) acc[mt][nt] = (floatx4){0.f, 0.f, 0.f, 0.f};

    float b2r[4], w3r[4];
#pragma unroll
    for (int nt = 0; nt < 4; ++nt) {
        b2r[nt] = bf2[nt * 16 + (l & 15)];
        w3r[nt] = Wf3[nt * 16 + (l & 15)];
    }

    const int rB = l & 15, kq = l >> 4;
#pragma unroll
    for (int kc = 0; kc < 4; ++kc)
#pragma unroll
        for (int ks = 0; ks < 2; ++ks) {
            const int kfb = (kc * 64 + ks * 32 + kq * 8) * 4;
            float4 b1a = *(const float4*)((char*)sB1 + ((rB * 1024 + kfb)      ^ ((rB & 7) << 5)));
            float4 b1b = *(const float4*)((char*)sB1 + ((rB * 1024 + kfb + 16) ^ ((rB & 7) << 5)));
            short8 afr[4];
#pragma unroll
            for (int mt = 0; mt < 4; ++mt) {
                int rA = w * 4 + mt;
                float4 a1a = *(const float4*)((char*)sA1 + rA * 1024 + kfb);
                float4 a1b = *(const float4*)((char*)sA1 + rA * 1024 + kfb + 16);
                short8 hv;
                hv[0] = (short)bfc(fmaxf(a1a.x + b1a.x, 0.f));
                hv[1] = (short)bfc(fmaxf(a1a.y + b1a.y, 0.f));
                hv[2] = (short)bfc(fmaxf(a1a.z + b1a.z, 0.f));
                hv[3] = (short)bfc(fmaxf(a1a.w + b1a.w, 0.f));
                hv[4] = (short)bfc(fmaxf(a1b.x + b1b.x, 0.f));
                hv[5] = (short)bfc(fmaxf(a1b.y + b1b.y, 0.f));
                hv[6] = (short)bfc(fmaxf(a1b.z + b1b.z, 0.f));
                hv[7] = (short)bfc(fmaxf(a1b.w + b1b.w, 0.f));
                afr[mt] = hv;
            }
            const int kwb = kc * 128 + ks * 64 + kq * 16;
            short8 bfr[4];
#pragma unroll
            for (int nt = 0; nt < 4; ++nt) {
                int n = nt * 16 + (l & 15);
                bfr[nt] = *(const short8*)((char*)sW + ((n * 512 + kwb) ^ ((n & 7) << 4)));
            }
#pragma unroll
            for (int mt = 0; mt < 4; ++mt)
#pragma unroll
                for (int nt = 0; nt < 4; ++nt)
                    acc[mt][nt] = __builtin_amdgcn_mfma_f32_16x16x32_bf16(afr[mt], bfr[nt], acc[mt][nt], 0, 0, 0);
        }

    const float b3 = bf3[0];
#pragma unroll
    for (int mt = 0; mt < 4; ++mt)
#pragma unroll
        for (int r = 0; r < 4; ++r) {
            float s = 0.f;
#pragma unroll
            for (int nt = 0; nt < 4; ++nt)
                s += fmaxf(acc[mt][nt][r] + b2r[nt], 0.f) * w3r[nt];
            s += __shfl_xor(s, 1); s += __shfl_xor(s, 2);
            s += __shfl_xor(s, 4); s += __shfl_xor(s, 8);
            if ((l & 15) == 0) {
                int p = w * 64 + mt * 16 + (l >> 4) * 4 + r;
                out[(size_t)(i0 + (p >> 4)) * NRES + j0 + (p & 15)] = s + b3;
            }
        }
}

// ---------------------------------------------------------------------------
extern "C" void kernel_launch(void* const* d_in, const int* in_sizes, int n_in,
                              void* d_out, int out_size, void* d_ws, size_t ws_size,
                              hipStream_t stream)
{
    const float* atoms0    = (const float*)d_in[0];
    const float* residues0 = (const float*)d_in[1];
    const int*   same0     = (const int*)d_in[2];
    const int*   diff0     = (const int*)d_in[3];
    const float* atoms1    = (const float*)d_in[5];
    const float* residues1 = (const float*)d_in[6];
    const int*   same1     = (const int*)d_in[7];
    const int*   diff1     = (const int*)d_in[8];
    const float* Wv   = (const float*)d_in[10];
    const float* Wr   = (const float*)d_in[11];
    const float* Wsr1 = (const float*)d_in[12];
    const float* Wdr1 = (const float*)d_in[13];
    const float* Wsv  = (const float*)d_in[14];
    const float* Wsr2 = (const float*)d_in[15];
    const float* Wdr2 = (const float*)d_in[16];
    const float* Wf1  = (const float*)d_in[17];
    const float* bf1  = (const float*)d_in[18];
    const float* Wf2  = (const float*)d_in[19];
    const float* bf2  = (const float*)d_in[20];
    const float* Wf3  = (const float*)d_in[21];
    const float* bf3  = (const float*)d_in[22];

    float* ws  = (float*)d_ws;
    float* ACC = ws;                                         // 2 x 2,048,000 f
    unsigned short* SD  = (unsigned short*)(ws + 4096000);   // 2 x 4,096,000 u16 (layer-1)
    unsigned short* SD2 = (unsigned short*)(ws + 8192000);   // 2 x 4,096,000 u16 (layer-2)
    float* A1  = ws + 12288000;                              // 102,400 f
    float* B1  = ws + 12390400;                              // 102,400 f
    unsigned short* WrT = (unsigned short*)(ws + 12492800);  // 131,072 u16
    unsigned short* Bt3 = (unsigned short*)(ws + 12558336);  //  49,152 u16
    unsigned short* W2T = (unsigned short*)(ws + 12582912);  //  16,384 u16

    k_prep<<<152, 256, 0, stream>>>(Wr, Wsv, Wsr2, Wdr2, Wf2, WrT, Bt3, W2T);
    k_mega1<<<dim3(500, 2), 256, 0, stream>>>(residues0, residues1, WrT,
                                              atoms0, atoms1, Wsr1, Wdr1, ACC, SD);
    k_gl2<<<dim3(500, 2), 256, 0, stream>>>(ACC, SD, Bt3, same0, diff0, same1, diff1,
                                            atoms0, atoms1, Wv, SD2);
    k_gather_res<<<dim3(NRES, 2), 256, 0, stream>>>(ACC, SD2, same0, diff0, same1, diff1,
                                                    Wf1, bf1, A1, B1);
    k_pairs_mfma<<<dim3(25, 25), 256, 0, stream>>>(A1, B1, W2T, bf2, Wf3, bf3, (float*)d_out);
}